// Round 6
// baseline (620.019 us; speedup 1.0000x reference)
//
#include <hip/hip_runtime.h>
#include <hip/hip_bf16.h>
#include <math.h>

#define L_SEQ 2048
#define DM 512
#define NH 8
#define HD 64
// log2(10000)/32
#define ROPE_C 0.4152410118609203f

typedef __attribute__((ext_vector_type(8))) short bf16x8;
typedef __attribute__((ext_vector_type(8))) unsigned short u16x8;
typedef __attribute__((ext_vector_type(4))) float f32x4;

#define MFMA16(a, b, c) __builtin_amdgcn_mfma_f32_16x16x32_bf16((a), (b), (c), 0, 0, 0)

static __device__ __forceinline__ unsigned short f2bf(float f) {
    union { float f; unsigned int u; } c; c.f = f;
    unsigned int r = (c.u + 0x7fffu + ((c.u >> 16) & 1u)) >> 16;
    return (unsigned short)r;
}
static __device__ __forceinline__ float bf2f(unsigned short h) {
    union { unsigned int u; float f; } c; c.u = ((unsigned int)h) << 16;
    return c.f;
}

// ---------------------------------------------------------------------------
// Kernel 1: QKV projection via MFMA hi/lo split (unchanged from round 3).
// ---------------------------------------------------------------------------
__global__ __launch_bounds__(256) void qkv_proj_mfma(
    const float* __restrict__ x,
    const float* __restrict__ Wq, const float* __restrict__ bq,
    const float* __restrict__ Wk, const float* __restrict__ bk,
    const float* __restrict__ Wv, const float* __restrict__ bv,
    unsigned short* __restrict__ Qh, unsigned short* __restrict__ Ql,
    unsigned short* __restrict__ Kh, unsigned short* __restrict__ Kl,
    unsigned short* __restrict__ Vb)
{
    const int z = blockIdx.z;
    const float* __restrict__ W    = (z == 0) ? Wq : (z == 1) ? Wk : Wv;
    const float* __restrict__ bias = (z == 0) ? bq : (z == 1) ? bk : bv;

    __shared__ __align__(16) unsigned short Xh[64 * 64];
    __shared__ __align__(16) unsigned short Xl[64 * 64];
    __shared__ __align__(16) unsigned short Wh[64 * 64];
    __shared__ __align__(16) unsigned short Wl[64 * 64];

    const int t = threadIdx.x;
    const int w = t >> 6, l = t & 63;
    const int lr = l & 15, lg = l >> 4;
    const int mbase = blockIdx.x * 64;
    const int nbase = blockIdx.y * 64;

    const int sr = t & 63;
    const int sc = (t >> 6) * 16;

    f32x4 acc[4];
    #pragma unroll
    for (int nb = 0; nb < 4; ++nb) acc[nb] = (f32x4){0.f, 0.f, 0.f, 0.f};

    for (int k0 = 0; k0 < DM; k0 += 64) {
        __syncthreads();
        {
            const int ch0 = (t >> 6) * 2, sw = sr & 7;
            const float* xs = &x[(size_t)(mbase + sr) * DM + k0 + sc];
            const float* ws = &W[(size_t)(nbase + sr) * DM + k0 + sc];
            float xv[16], wv[16];
            #pragma unroll
            for (int i = 0; i < 4; ++i) {
                float4 a = *(const float4*)(xs + 4 * i);
                xv[4 * i + 0] = a.x; xv[4 * i + 1] = a.y; xv[4 * i + 2] = a.z; xv[4 * i + 3] = a.w;
                float4 b = *(const float4*)(ws + 4 * i);
                wv[4 * i + 0] = b.x; wv[4 * i + 1] = b.y; wv[4 * i + 2] = b.z; wv[4 * i + 3] = b.w;
            }
            u16x8 xh0, xl0, xh1, xl1, wh0, wl0, wh1, wl1;
            #pragma unroll
            for (int i = 0; i < 8; ++i) {
                unsigned short h;
                h = f2bf(xv[i]);     xh0[i] = h; xl0[i] = f2bf(xv[i] - bf2f(h));
                h = f2bf(xv[i + 8]); xh1[i] = h; xl1[i] = f2bf(xv[i + 8] - bf2f(h));
                h = f2bf(wv[i]);     wh0[i] = h; wl0[i] = f2bf(wv[i] - bf2f(h));
                h = f2bf(wv[i + 8]); wh1[i] = h; wl1[i] = f2bf(wv[i + 8] - bf2f(h));
            }
            *(u16x8*)&Xh[sr * 64 + (((ch0    ) ^ sw) << 3)] = xh0;
            *(u16x8*)&Xh[sr * 64 + (((ch0 + 1) ^ sw) << 3)] = xh1;
            *(u16x8*)&Xl[sr * 64 + (((ch0    ) ^ sw) << 3)] = xl0;
            *(u16x8*)&Xl[sr * 64 + (((ch0 + 1) ^ sw) << 3)] = xl1;
            *(u16x8*)&Wh[sr * 64 + (((ch0    ) ^ sw) << 3)] = wh0;
            *(u16x8*)&Wh[sr * 64 + (((ch0 + 1) ^ sw) << 3)] = wh1;
            *(u16x8*)&Wl[sr * 64 + (((ch0    ) ^ sw) << 3)] = wl0;
            *(u16x8*)&Wl[sr * 64 + (((ch0 + 1) ^ sw) << 3)] = wl1;
        }
        __syncthreads();

        #pragma unroll
        for (int kc = 0; kc < 2; ++kc) {
            const int arow = w * 16 + lr;
            const int aofs = arow * 64 + (((4 * kc + lg) ^ (arow & 7)) << 3);
            bf16x8 ah = *(const bf16x8*)&Xh[aofs];
            bf16x8 al = *(const bf16x8*)&Xl[aofs];
            #pragma unroll
            for (int nb = 0; nb < 4; ++nb) {
                const int brow = nb * 16 + lr;
                const int bofs = brow * 64 + (((4 * kc + lg) ^ (brow & 7)) << 3);
                bf16x8 bh_ = *(const bf16x8*)&Wh[bofs];
                bf16x8 bl_ = *(const bf16x8*)&Wl[bofs];
                acc[nb] = MFMA16(ah, bl_, acc[nb]);
                acc[nb] = MFMA16(al, bh_, acc[nb]);
                acc[nb] = MFMA16(ah, bh_, acc[nb]);
            }
        }
    }

    #pragma unroll
    for (int nb = 0; nb < 4; ++nb) {
        const int n    = nbase + nb * 16 + lr;
        const int head = n >> 6;
        const int dim  = n & 63;
        const float bval = bias[n];
        const float invf = exp2f(-ROPE_C * (float)(dim >> 1));
        #pragma unroll
        for (int r = 0; r < 4; ++r) {
            const int mg    = mbase + w * 16 + lg * 4 + r;
            const int batch = mg >> 11;
            const int pos   = mg & 2047;
            float v = acc[nb][r] + bval;
            if (z < 2) {
                const float pv = __shfl_xor(v, 1);
                float s, c;
                sincosf((float)pos * invf, &s, &c);
                v = (dim & 1) ? fmaf(v, c, pv * s) : fmaf(v, c, -pv * s);
            }
            const size_t oidx = (((size_t)(batch * NH + head)) * L_SEQ + pos) * HD + dim;
            if (z == 2) {
                Vb[oidx] = f2bf(v);
            } else {
                const unsigned short h  = f2bf(v);
                const unsigned short lo = f2bf(v - bf2f(h));
                if (z == 0) { Qh[oidx] = h; Ql[oidx] = lo; }
                else        { Kh[oidx] = h; Kl[oidx] = lo; }
            }
        }
    }
}

// ---------------------------------------------------------------------------
// Kernel 2: fused causal attention, MFMA, UNIFORM-WORK blocks.
// Block = (head bh, pair of 32-row q-tiles {qtA, 63-qtA}). 4 waves:
//   waves 0,1 -> tile A (rows 32*qtA + 16*(w&1))
//   waves 2,3 -> tile B (rows 32*qtB + 16*(w&1)), qtB = 63-qtA
// One shared k-sweep of nkt(qtB) 64-wide tiles; waves with finished tiles
// keep staging+barriers but skip compute. Per-block work = 33-34 tile-iters
// for every block => uniform makespan (fixes the 1.94x LPT tail of round 3).
// grid: 512 (x = qtA*16 + bh; bh in low bits => 2 heads per XCD L2).
// ---------------------------------------------------------------------------
__global__ __launch_bounds__(256) void attn_mfma(
    const unsigned short* __restrict__ Qh, const unsigned short* __restrict__ Ql,
    const unsigned short* __restrict__ Kh, const unsigned short* __restrict__ Kl,
    const unsigned short* __restrict__ Vb, const float* __restrict__ prev,
    float* __restrict__ out_o, float* __restrict__ out_score)
{
    __shared__ __align__(16) unsigned short Ksh[64 * 64];
    __shared__ __align__(16) unsigned short Ksl[64 * 64];
    __shared__ __align__(16) unsigned short Vt[64 * 64];
    __shared__ __align__(16) unsigned short Ps[4 * 16 * 64];

    const int g   = blockIdx.x;
    const int bh  = g & 15;
    const int qtA = g >> 4;          // 0..31
    const int qtB = 63 - qtA;        // 32..63
    const int t   = threadIdx.x;
    const int w   = t >> 6, l = t & 63;
    const int lr  = l & 15, lg = l >> 4;

    const int myQt    = (w < 2) ? qtA : qtB;
    const int myQbase = myQt * 32 + (w & 1) * 16;
    const int myNkt   = myQt / 2 + 1;
    const int sweep   = qtB / 2 + 1;

    const size_t hbase = (size_t)bh * L_SEQ * HD;

    // per-wave Q a-frags (16 rows at myQbase)
    bf16x8 qhf[2], qlf[2];
    {
        const size_t qoff = hbase + (size_t)(myQbase + lr) * HD + lg * 8;
        qhf[0] = *(const bf16x8*)&Qh[qoff];
        qhf[1] = *(const bf16x8*)&Qh[qoff + 32];
        qlf[0] = *(const bf16x8*)&Ql[qoff];
        qlf[1] = *(const bf16x8*)&Ql[qoff + 32];
    }

    f32x4 accO[4];
    #pragma unroll
    for (int db = 0; db < 4; ++db) accO[db] = (f32x4){0.f, 0.f, 0.f, 0.f};
    float m_i[4] = {-INFINITY, -INFINITY, -INFINITY, -INFINITY};
    float l_i[4] = {0.f, 0.f, 0.f, 0.f};

    const size_t srow0 = ((size_t)bh * L_SEQ + myQbase) * L_SEQ;

    for (int kt = 0; kt < sweep; ++kt) {
        const int kbase = kt << 6;
        const bool active = (kt < myNkt);     // wave-uniform
        __syncthreads();   // previous iteration done with Ksh/Ksl/Vt

        // prev loads issued early (latency hides under staging)
        const size_t srow = srow0 + kbase;
        float pvv[4][4];
        if (active) {
            #pragma unroll
            for (int kb = 0; kb < 4; ++kb)
                #pragma unroll
                for (int r = 0; r < 4; ++r)
                    pvv[kb][r] = prev[srow + (size_t)(lg * 4 + r) * L_SEQ + kb * 16 + lr];
        }

        // cooperative staging: K hi/lo (swizzled rows) + V transposed
        {
            const int r = t & 63, c32 = t >> 6;
            const int ch0 = 2 * c32, sw = r & 7;
            const size_t koff = hbase + (size_t)(kbase + r) * HD + c32 * 16;
            u16x8 k0 = *(const u16x8*)&Kh[koff];
            u16x8 k1 = *(const u16x8*)&Kh[koff + 8];
            *(u16x8*)&Ksh[r * 64 + (((ch0    ) ^ sw) << 3)] = k0;
            *(u16x8*)&Ksh[r * 64 + (((ch0 + 1) ^ sw) << 3)] = k1;
            u16x8 k2 = *(const u16x8*)&Kl[koff];
            u16x8 k3 = *(const u16x8*)&Kl[koff + 8];
            *(u16x8*)&Ksl[r * 64 + (((ch0    ) ^ sw) << 3)] = k2;
            *(u16x8*)&Ksl[r * 64 + (((ch0 + 1) ^ sw) << 3)] = k3;

            const int vk = t & 63, vd0 = (t >> 6) * 16;
            const size_t voff = hbase + (size_t)(kbase + vk) * HD + vd0;
            u16x8 va  = *(const u16x8*)&Vb[voff];
            u16x8 vb2 = *(const u16x8*)&Vb[voff + 8];
            #pragma unroll
            for (int e = 0; e < 8; ++e) {
                int d = vd0 + e;
                Vt[d * 64 + ((((vk >> 3) ^ (d & 7))) << 3) + (vk & 7)] = va[e];
                d = vd0 + 8 + e;
                Vt[d * 64 + ((((vk >> 3) ^ (d & 7))) << 3) + (vk & 7)] = vb2[e];
            }
        }
        __syncthreads();

        if (active) {
            // S = Q K^T (3-term hi/lo split)
            f32x4 s[4];
            #pragma unroll
            for (int kb = 0; kb < 4; ++kb) s[kb] = (f32x4){0.f, 0.f, 0.f, 0.f};
            #pragma unroll
            for (int kc = 0; kc < 2; ++kc) {
                #pragma unroll
                for (int kb = 0; kb < 4; ++kb) {
                    const int brow = kb * 16 + lr;
                    const int bofs = brow * 64 + (((4 * kc + lg) ^ (brow & 7)) << 3);
                    bf16x8 bh_ = *(const bf16x8*)&Ksh[bofs];
                    bf16x8 bl_ = *(const bf16x8*)&Ksl[bofs];
                    s[kb] = MFMA16(qhf[kc], bl_, s[kb]);
                    s[kb] = MFMA16(qlf[kc], bh_, s[kb]);
                    s[kb] = MFMA16(qhf[kc], bh_, s[kb]);
                }
            }

            // scale + mask + prev, score store
            float vout[4][4];
            #pragma unroll
            for (int kb = 0; kb < 4; ++kb) {
                #pragma unroll
                for (int r = 0; r < 4; ++r) {
                    const int kg = kbase + kb * 16 + lr;
                    const int qg = myQbase + lg * 4 + r;
                    const float v = (kg <= qg) ? fmaf(s[kb][r], 0.125f, pvv[kb][r]) : -1e9f;
                    vout[kb][r] = v;
                    out_score[srow + (size_t)(lg * 4 + r) * L_SEQ + kb * 16 + lr] = v;
                }
            }

            // online softmax (row groups of 16 lanes)
            #pragma unroll
            for (int r = 0; r < 4; ++r) {
                float mx = fmaxf(fmaxf(vout[0][r], vout[1][r]), fmaxf(vout[2][r], vout[3][r]));
                mx = fmaxf(mx, __shfl_xor(mx, 1));
                mx = fmaxf(mx, __shfl_xor(mx, 2));
                mx = fmaxf(mx, __shfl_xor(mx, 4));
                mx = fmaxf(mx, __shfl_xor(mx, 8));
                const float mnew = fmaxf(m_i[r], mx);
                const float sc = __expf(m_i[r] - mnew);   // kt=0: exp(-inf)=0
                float p[4], psum = 0.f;
                #pragma unroll
                for (int kb = 0; kb < 4; ++kb) { p[kb] = __expf(vout[kb][r] - mnew); psum += p[kb]; }
                psum += __shfl_xor(psum, 1);
                psum += __shfl_xor(psum, 2);
                psum += __shfl_xor(psum, 4);
                psum += __shfl_xor(psum, 8);
                l_i[r] = l_i[r] * sc + psum;
                m_i[r] = mnew;
                #pragma unroll
                for (int db = 0; db < 4; ++db) accO[db][r] *= sc;
                const int qloc = lg * 4 + r, swp = qloc & 7;
                #pragma unroll
                for (int kb = 0; kb < 4; ++kb) {
                    const int kcol = kb * 16 + lr;
                    Ps[w * 1024 + qloc * 64 + ((((kcol >> 3) ^ swp)) << 3) + (kcol & 7)] = f2bf(p[kb]);
                }
            }

            // O += P V   (Ps wave-private; Vt shared)
            #pragma unroll
            for (int kc = 0; kc < 2; ++kc) {
                const int aofs = w * 1024 + lr * 64 + (((4 * kc + lg) ^ (lr & 7)) << 3);
                bf16x8 pa = *(const bf16x8*)&Ps[aofs];
                #pragma unroll
                for (int db = 0; db < 4; ++db) {
                    const int vrow = db * 16 + lr;
                    const int bofs = vrow * 64 + (((4 * kc + lg) ^ (vrow & 7)) << 3);
                    bf16x8 vf = *(const bf16x8*)&Vt[bofs];
                    accO[db] = MFMA16(pa, vf, accO[db]);
                }
            }
        }
    }

    // epilogue: O /= l
    const int bb = bh >> 3, hh = bh & 7;
    #pragma unroll
    for (int r = 0; r < 4; ++r) {
        const int qg = myQbase + lg * 4 + r;
        const float inv = 1.0f / l_i[r];
        #pragma unroll
        for (int db = 0; db < 4; ++db)
            out_o[((size_t)bb * L_SEQ + qg) * DM + hh * HD + db * 16 + lr] = accO[db][r] * inv;
    }

    // strictly-upper fill: exactly -1e9 (|prev| < half-ulp(1e9)).
    // Per-wave: own 16 rows, cols [64*myNkt, 2048). Uniform per block by pairing.
    {
        const int c0 = myNkt << 6;
        const int row = myQbase + lr;
        const size_t rb = ((size_t)bh * L_SEQ + row) * L_SEQ;
        const float4 fv = make_float4(-1e9f, -1e9f, -1e9f, -1e9f);
        for (int c = c0 + lg * 4; c < L_SEQ; c += 16)
            *(float4*)&out_score[rb + c] = fv;
    }
}

// ---------------------------------------------------------------------------
extern "C" void kernel_launch(void* const* d_in, const int* in_sizes, int n_in,
                              void* d_out, int out_size, void* d_ws, size_t ws_size,
                              hipStream_t stream)
{
    const float* x    = (const float*)d_in[0];
    const float* prev = (const float*)d_in[1];
    const float* Wq   = (const float*)d_in[2];
    const float* bq   = (const float*)d_in[3];
    const float* Wk   = (const float*)d_in[4];
    const float* bk   = (const float*)d_in[5];
    const float* Wv   = (const float*)d_in[6];
    const float* bv   = (const float*)d_in[7];

    float* out_o     = (float*)d_out;
    float* out_score = out_o + (size_t)2 * L_SEQ * DM;

    const size_t qkv_elems = (size_t)2 * NH * L_SEQ * HD;
    unsigned short* Qh = (unsigned short*)d_ws;
    unsigned short* Ql = Qh + qkv_elems;
    unsigned short* Kh = Ql + qkv_elems;
    unsigned short* Kl = Kh + qkv_elems;
    unsigned short* Vb = Kl + qkv_elems;

    qkv_proj_mfma<<<dim3(64, 8, 3), 256, 0, stream>>>(
        x, Wq, bq, Wk, bk, Wv, bv, Qh, Ql, Kh, Kl, Vb);

    attn_mfma<<<dim3(512), 256, 0, stream>>>(
        Qh, Ql, Kh, Kl, Vb, prev, out_o, out_score);
}